// Round 3
// baseline (2142.065 us; speedup 1.0000x reference)
//
#include <hip/hip_runtime.h>

typedef _Float16 h2  __attribute__((ext_vector_type(2)));
typedef _Float16 h8  __attribute__((ext_vector_type(8)));
typedef float    f4  __attribute__((ext_vector_type(4)));
typedef short    s8  __attribute__((ext_vector_type(8)));

#define NTOK 65536              // B*L = 32*2048
#define L_ 2048

// workspace layout (bytes), total exactly 192 MiB:
//   xp_rz : NTOK*768  f16  = 100,663,296   [tok][dir][j][{r,z}]
//   xp_n  : NTOK*384  f16  =  50,331,648   [tok][dir][j]
//   allh  : NTOK*384  bf16 =  50,331,648   [b][pos][dir*192+j]
#define XP_RZ_BYTES ((size_t)NTOK * 768 * 2)
#define XP_N_BYTES  ((size_t)NTOK * 384 * 2)

__device__ __forceinline__ float bf2f(unsigned short u){
    union { unsigned int i; float f; } v; v.i = ((unsigned)u) << 16; return v.f;
}
__device__ __forceinline__ unsigned short f2bf(float f){
    union { float f; unsigned int i; } v; v.f = f;
    unsigned int r = v.i + 0x7FFFu + ((v.i >> 16) & 1u);   // RNE, finite inputs
    return (unsigned short)(r >> 16);
}

// Runtime dtype sniff: for uniform(+-0.072) data stored as bf16, every 16-bit
// half has exponent <= 123. Stored as f32, low halves are uniform mantissa bits
// -> ~51% have bf16-exponent >= 126. All waves read the same 64 dwords, so the
// result is block-uniform and identical on every call (graph-capture safe).
__device__ __forceinline__ bool sniff_f32(const void* w){
    const unsigned* p = (const unsigned*)w;
    unsigned d = p[threadIdx.x & 63];
    unsigned ex = (d >> 7) & 0xFFu;             // exponent of low half as bf16
    unsigned long long m = __ballot(ex >= 126u);
    return __popcll(m) >= 4;
}

// load 8 contiguous logical elements (f32 or bf16 source) as 8 bf16 into dst
__device__ __forceinline__ void load8_bf16(void* dst, const void* src, long off, bool f32m){
    if (f32m){
        const float* p = (const float*)src + off;          // off%8==0 -> 32B aligned
        f4 a = *(const f4*)p;
        f4 b = *(const f4*)(p + 4);
        unsigned short o[8] = {f2bf(a[0]),f2bf(a[1]),f2bf(a[2]),f2bf(a[3]),
                               f2bf(b[0]),f2bf(b[1]),f2bf(b[2]),f2bf(b[3])};
        *(uint4*)dst = *(const uint4*)o;
    } else {
        *(uint4*)dst = *(const uint4*)((const unsigned short*)src + off);
    }
}
__device__ __forceinline__ float ldscal(const void* src, long off, bool f32m){
    return f32m ? ((const float*)src)[off] : bf2f(((const unsigned short*)src)[off]);
}
__device__ __forceinline__ float quad_allreduce(float v){
    int x = __builtin_amdgcn_update_dpp(0, __float_as_int(v), 0xB1, 0xF, 0xF, true); // quad_perm(1,0,3,2)
    v += __int_as_float(x);
    x = __builtin_amdgcn_update_dpp(0, __float_as_int(v), 0x4E, 0xF, 0xF, true);     // quad_perm(2,3,0,1)
    v += __int_as_float(x);
    return v;
}

// ---------------- Kernel 1: embedding gather + dual-direction input projection ----------------
__global__ __launch_bounds__(256) void k_proj(
    const int* __restrict__ ids,
    const void* __restrict__ emb,
    const void* __restrict__ wf,
    const void* __restrict__ wb,
    const void* __restrict__ bf_,
    const void* __restrict__ bb_,
    _Float16* __restrict__ xp_rz,
    _Float16* __restrict__ xp_n)
{
    const bool f32m = sniff_f32(wf);
    __shared__ __align__(16) unsigned short As[128][72];   // 64 K + 8 pad
    __shared__ __align__(16) unsigned short Bs[128][72];
    const int mBase = blockIdx.x * 128;
    const int nBase = blockIdx.y * 128;      // over 1152 = [f:576 | b:576], each gate*192+j
    const int tid = threadIdx.x;
    const int w = tid >> 6, lane = tid & 63;
    const int quad = lane >> 4, col = lane & 15;
    f4 acc[2][8] = {};
    for (int k0 = 0; k0 < 256; k0 += 64){
        __syncthreads();
        #pragma unroll
        for (int i = 0; i < 4; ++i){
            int cc = tid + i*256;
            int row = cc >> 3, c8 = cc & 7;
            int id = ids[mBase + row];
            id = (id < 0) ? 0 : ((id > 1000) ? 1000 : id);   // clamp: diagnostic insurance
            load8_bf16(&As[row][c8*8], emb, (long)id*256 + k0 + c8*8, f32m);
        }
        #pragma unroll
        for (int i = 0; i < 4; ++i){
            int cc = tid + i*256;
            int row = cc >> 3, c8 = cc & 7;
            int g = nBase + row;
            const void* src = (g < 576) ? wf : wb;
            long goff = (g < 576) ? g : (g - 576);
            load8_bf16(&Bs[row][c8*8], src, goff*256 + k0 + c8*8, f32m);
        }
        __syncthreads();
        #pragma unroll
        for (int s = 0; s < 2; ++s){
            int ko = s*32 + quad*8;
            s8 a0 = *(const s8*)(&As[(w<<5) + col][ko]);
            s8 a1 = *(const s8*)(&As[(w<<5) + 16 + col][ko]);
            #pragma unroll
            for (int nt = 0; nt < 8; ++nt){
                s8 bv = *(const s8*)(&Bs[nt*16 + col][ko]);
                acc[0][nt] = __builtin_amdgcn_mfma_f32_16x16x32_bf16(a0, bv, acc[0][nt], 0,0,0);
                acc[1][nt] = __builtin_amdgcn_mfma_f32_16x16x32_bf16(a1, bv, acc[1][nt], 0,0,0);
            }
        }
    }
    // D layout: col = lane&15 (N), row = quad*4 + reg (M)  [m89-verified]
    #pragma unroll
    for (int nt = 0; nt < 8; ++nt){
        int g = nBase + nt*16 + col;
        int dir = (g >= 576) ? 1 : 0;
        int rr = g - dir*576;
        int gate = rr / 192;
        int j = rr - gate*192;
        float bias = ldscal(dir ? bb_ : bf_, rr, f32m);
        #pragma unroll
        for (int mt = 0; mt < 2; ++mt){
            #pragma unroll
            for (int r = 0; r < 4; ++r){
                int m = mBase + (w<<5) + mt*16 + quad*4 + r;
                float v = acc[mt][nt][r] + bias;
                if (gate < 2) xp_rz[(size_t)m*768 + dir*384 + j*2 + gate] = (_Float16)v;
                else          xp_n [(size_t)m*384 + dir*192 + j]          = (_Float16)v;
            }
        }
    }
}

// ---------------- Kernel 2: GRU scan, one block per (batch, direction) ----------------
// 768 threads = 192 units x 4 lanes; lane c covers k in [48c, 48c+48)
__global__ __launch_bounds__(768, 3) void k_scan(
    const void* __restrict__ whh_f,
    const void* __restrict__ bhh_f,
    const void* __restrict__ whh_b,
    const void* __restrict__ bhh_b,
    const _Float16* __restrict__ xp_rz,
    const _Float16* __restrict__ xp_n,
    unsigned short* __restrict__ allh)
{
    const bool f32m = sniff_f32(whh_f);
    __shared__ __align__(16) _Float16 hbuf[2][192];
    const int bd = blockIdx.x;
    const int b = bd >> 1, dir = bd & 1;
    const int tid = threadIdx.x;
    const int j = tid >> 2, c = tid & 3;
    const void* whh = dir ? whh_b : whh_f;
    const void* bhh = dir ? bhh_b : bhh_f;

    // W_hh in VGPRs as f16 (from f32: 2^-11 rel err; from bf16: exact)
    h2 wr[24], wz[24], wn[24];
    {
        long r0 = (long)(0*192 + j)*192 + c*48;
        long r1 = (long)(1*192 + j)*192 + c*48;
        long r2 = (long)(2*192 + j)*192 + c*48;
        #pragma unroll
        for (int kk = 0; kk < 24; ++kk){
            wr[kk] = h2{(_Float16)ldscal(whh, r0+2*kk, f32m), (_Float16)ldscal(whh, r0+2*kk+1, f32m)};
            wz[kk] = h2{(_Float16)ldscal(whh, r1+2*kk, f32m), (_Float16)ldscal(whh, r1+2*kk+1, f32m)};
            wn[kk] = h2{(_Float16)ldscal(whh, r2+2*kk, f32m), (_Float16)ldscal(whh, r2+2*kk+1, f32m)};
        }
    }
    const float bhr = ldscal(bhh, j, f32m);
    const float bhz = ldscal(bhh, 192 + j, f32m);
    const float bhn = ldscal(bhh, 384 + j, f32m);

    if (tid < 192) hbuf[0][tid] = (_Float16)0.f;
    __syncthreads();

    const _Float16* xrz = xp_rz + (size_t)b*L_*768 + dir*384 + j*2;
    const _Float16* xnp = xp_n  + (size_t)b*L_*384 + dir*192 + j;
    unsigned short* hout = allh + (size_t)b*L_*384 + dir*192 + j;

    float hprev = 0.f;
    h2 px0 = h2{(_Float16)0.f,(_Float16)0.f}, px1 = px0;
    _Float16 pn0 = (_Float16)0.f, pn1 = pn0;
    if (c == 0){
        int q0 = dir ? (L_-1) : 0, q1 = dir ? (L_-2) : 1;
        px0 = *(const h2*)(xrz + (size_t)q0*768); pn0 = xnp[(size_t)q0*384];
        px1 = *(const h2*)(xrz + (size_t)q1*768); pn1 = xnp[(size_t)q1*384];
    }

    for (int t = 0; t < L_; ++t){
        h2 px2 = px1; _Float16 pn2 = pn1;
        if (c == 0){
            int tn = (t + 2 < L_) ? (t + 2) : (L_-1);
            int posn = dir ? (L_-1 - tn) : tn;
            px2 = *(const h2*)(xrz + (size_t)posn*768);
            pn2 = xnp[(size_t)posn*384];
        }

        const int cur = t & 1, nxt = cur ^ 1;
        float ar = 0.f, az = 0.f, an = 0.f;
        const h8* hp = (const h8*)(&hbuf[cur][c*48]);
        #pragma unroll
        for (int i = 0; i < 6; ++i){
            h8 hv = hp[i];
            #pragma unroll
            for (int q = 0; q < 4; ++q){
                h2 hx = h2{hv[2*q], hv[2*q+1]};
                ar = __builtin_amdgcn_fdot2(wr[i*4+q], hx, ar, false);
                az = __builtin_amdgcn_fdot2(wz[i*4+q], hx, az, false);
                an = __builtin_amdgcn_fdot2(wn[i*4+q], hx, an, false);
            }
        }
        ar = quad_allreduce(ar);
        az = quad_allreduce(az);
        an = quad_allreduce(an);

        if (c == 0){
            float xr = (float)px0[0], xz = (float)px0[1], xn = (float)pn0;
            float r = __builtin_amdgcn_rcpf(1.f + __expf(-(xr + ar + bhr)));
            float z = __builtin_amdgcn_rcpf(1.f + __expf(-(xz + az + bhz)));
            float narg = fmaf(r, an + bhn, xn);
            float nv = fmaf(2.f, __builtin_amdgcn_rcpf(1.f + __expf(-2.f*narg)), -1.f);
            float h = fmaf(z, hprev - nv, nv);
            hprev = h;
            hbuf[nxt][j] = (_Float16)h;
            int pos = dir ? (L_-1 - t) : t;
            hout[(size_t)pos*384] = f2bf(h);
        }
        px0 = px1; pn0 = pn1;
        px1 = px2; pn1 = pn2;
        __syncthreads();   // conservative full barrier (includes vmcnt drain)
    }
}

// ---------------- Kernel 3: start/end gather, output dtype follows input dtype ----------------
__global__ __launch_bounds__(256) void k_gather(
    const int* __restrict__ start_ids,
    const int* __restrict__ end_ids,
    const unsigned short* __restrict__ allh,
    const void* __restrict__ sniff_src,
    void* __restrict__ out)
{
    const bool f32m = sniff_f32(sniff_src);
    int t = blockIdx.x * 256 + threadIdx.x;       // 1,572,864 threads, 8 elems each
    int k8 = t % 96;
    int rest = t / 96;
    int s = rest & 511;
    int b = rest >> 9;
    int k = k8 * 8;
    int off, pos;
    if (k < 384){ off = k;       pos = start_ids[b*512 + s]; }
    else        { off = k - 384; pos = end_ids  [b*512 + s]; }
    pos = (pos < 0) ? 0 : ((pos > 2047) ? 2047 : pos);       // clamp: diagnostic insurance
    const unsigned short* src = allh + (size_t)(b*2048 + pos)*384 + off;
    if (f32m){
        float* outf = (float*)out + (size_t)t*8;
        uint4 v = *(const uint4*)src;
        const unsigned short* h = (const unsigned short*)&v;
        f4 lo = {bf2f(h[0]), bf2f(h[1]), bf2f(h[2]), bf2f(h[3])};
        f4 hi = {bf2f(h[4]), bf2f(h[5]), bf2f(h[6]), bf2f(h[7])};
        *(f4*)outf = lo;
        *(f4*)(outf + 4) = hi;
    } else {
        uint4 v = *(const uint4*)src;
        *(uint4*)((unsigned short*)out + (size_t)t*8) = v;
    }
}

extern "C" void kernel_launch(void* const* d_in, const int* in_sizes, int n_in,
                              void* d_out, int out_size, void* d_ws, size_t ws_size,
                              hipStream_t stream)
{
    const int* ids   = (const int*)d_in[0];
    const int* sids  = (const int*)d_in[1];
    const int* eids  = (const int*)d_in[2];
    const void* emb  = d_in[3];
    const void* wihf = d_in[4];
    const void* whhf = d_in[5];
    const void* bihf = d_in[6];
    const void* bhhf = d_in[7];
    const void* wihb = d_in[8];
    const void* whhb = d_in[9];
    const void* bihb = d_in[10];
    const void* bhhb = d_in[11];

    _Float16* xp_rz = (_Float16*)d_ws;
    _Float16* xp_n  = (_Float16*)((char*)d_ws + XP_RZ_BYTES);
    unsigned short* allh = (unsigned short*)((char*)d_ws + XP_RZ_BYTES + XP_N_BYTES);

    dim3 g1(512, 9);   // 512 M-tiles x 9 N-tiles (1152/128)
    k_proj<<<g1, 256, 0, stream>>>(ids, emb, wihf, wihb, bihf, bihb, xp_rz, xp_n);
    k_scan<<<64, 768, 0, stream>>>(whhf, bhhf, whhb, bhhb, xp_rz, xp_n, allh);
    k_gather<<<6144, 256, 0, stream>>>(sids, eids, allh, whhf, d_out);
}

// Round 4
// 1897.063 us; speedup vs baseline: 1.1291x; 1.1291x over previous
//
#include <hip/hip_runtime.h>

typedef _Float16 h2  __attribute__((ext_vector_type(2)));
typedef _Float16 h8  __attribute__((ext_vector_type(8)));
typedef float    f4  __attribute__((ext_vector_type(4)));
typedef short    s8  __attribute__((ext_vector_type(8)));

#define NTOK 65536              // B*L = 32*2048
#define L_ 2048

// workspace layout (bytes), total exactly 192 MiB (validated fits in round 3):
//   xp_rz : NTOK*768  f16  = 100,663,296   [tok][dir][j][{r,z}]
//   xp_n  : NTOK*384  f16  =  50,331,648   [tok][dir][j]
//   allh  : NTOK*384  bf16 =  50,331,648   [b][pos][dir*192+j]
#define XP_RZ_BYTES ((size_t)NTOK * 768 * 2)
#define XP_N_BYTES  ((size_t)NTOK * 384 * 2)

__device__ __forceinline__ unsigned short f2bf(float f){
    union { float f; unsigned int i; } v; v.f = f;
    unsigned int r = v.i + 0x7FFFu + ((v.i >> 16) & 1u);   // RNE, finite inputs
    return (unsigned short)(r >> 16);
}
__device__ __forceinline__ float bf2f(unsigned short u){
    union { unsigned int i; float f; } v; v.i = ((unsigned)u) << 16; return v.f;
}
// 8 contiguous f32 -> 8 bf16
__device__ __forceinline__ void load8_f32_bf16(void* dst, const float* p){
    f4 a = *(const f4*)p;
    f4 b = *(const f4*)(p + 4);
    unsigned short o[8] = {f2bf(a[0]),f2bf(a[1]),f2bf(a[2]),f2bf(a[3]),
                           f2bf(b[0]),f2bf(b[1]),f2bf(b[2]),f2bf(b[3])};
    *(uint4*)dst = *(const uint4*)o;
}
__device__ __forceinline__ float quad_allreduce(float v){
    int x = __builtin_amdgcn_update_dpp(0, __float_as_int(v), 0xB1, 0xF, 0xF, true); // quad_perm(1,0,3,2)
    v += __int_as_float(x);
    x = __builtin_amdgcn_update_dpp(0, __float_as_int(v), 0x4E, 0xF, 0xF, true);     // quad_perm(2,3,0,1)
    v += __int_as_float(x);
    return v;
}

// ---------------- Kernel 1: embedding gather + dual-direction input projection ----------------
__global__ __launch_bounds__(256) void k_proj(
    const int* __restrict__ ids,
    const float* __restrict__ emb,
    const float* __restrict__ wf,
    const float* __restrict__ wb,
    const float* __restrict__ bf_,
    const float* __restrict__ bb_,
    _Float16* __restrict__ xp_rz,
    _Float16* __restrict__ xp_n)
{
    __shared__ __align__(16) unsigned short As[128][72];   // 64 K + 8 pad
    __shared__ __align__(16) unsigned short Bs[128][72];
    const int mBase = blockIdx.x * 128;
    const int nBase = blockIdx.y * 128;      // over 1152 = [f:576 | b:576], each gate*192+j
    const int tid = threadIdx.x;
    const int w = tid >> 6, lane = tid & 63;
    const int quad = lane >> 4, col = lane & 15;
    f4 acc[2][8] = {};
    for (int k0 = 0; k0 < 256; k0 += 64){
        __syncthreads();
        #pragma unroll
        for (int i = 0; i < 4; ++i){
            int cc = tid + i*256;
            int row = cc >> 3, c8 = cc & 7;
            int id = ids[mBase + row];
            id = (id < 0) ? 0 : ((id > 1000) ? 1000 : id);
            load8_f32_bf16(&As[row][c8*8], emb + (long)id*256 + k0 + c8*8);
        }
        #pragma unroll
        for (int i = 0; i < 4; ++i){
            int cc = tid + i*256;
            int row = cc >> 3, c8 = cc & 7;
            int g = nBase + row;
            const float* src = (g < 576) ? (wf + (long)g*256) : (wb + (long)(g-576)*256);
            load8_f32_bf16(&Bs[row][c8*8], src + k0 + c8*8);
        }
        __syncthreads();
        #pragma unroll
        for (int s = 0; s < 2; ++s){
            int ko = s*32 + quad*8;
            s8 a0 = *(const s8*)(&As[(w<<5) + col][ko]);
            s8 a1 = *(const s8*)(&As[(w<<5) + 16 + col][ko]);
            #pragma unroll
            for (int nt = 0; nt < 8; ++nt){
                s8 bv = *(const s8*)(&Bs[nt*16 + col][ko]);
                acc[0][nt] = __builtin_amdgcn_mfma_f32_16x16x32_bf16(a0, bv, acc[0][nt], 0,0,0);
                acc[1][nt] = __builtin_amdgcn_mfma_f32_16x16x32_bf16(a1, bv, acc[1][nt], 0,0,0);
            }
        }
    }
    // D layout: col = lane&15 (N), row = quad*4 + reg (M)  [m89-verified]
    #pragma unroll
    for (int nt = 0; nt < 8; ++nt){
        int g = nBase + nt*16 + col;
        int dir = (g >= 576) ? 1 : 0;
        int rr = g - dir*576;
        int gate = rr / 192;
        int j = rr - gate*192;
        float bias = dir ? bb_[rr] : bf_[rr];
        #pragma unroll
        for (int mt = 0; mt < 2; ++mt){
            #pragma unroll
            for (int r = 0; r < 4; ++r){
                int m = mBase + (w<<5) + mt*16 + quad*4 + r;
                float v = acc[mt][nt][r] + bias;
                if (gate < 2) xp_rz[(size_t)m*768 + dir*384 + j*2 + gate] = (_Float16)v;
                else          xp_n [(size_t)m*384 + dir*192 + j]          = (_Float16)v;
            }
        }
    }
}

// ---------------- Kernel 2: GRU scan, one block per (batch, direction) ----------------
// 768 threads = 192 units x 4 lanes; lane c covers k in [48c, 48c+48)
__global__ __launch_bounds__(768, 3) void k_scan(
    const float* __restrict__ whh_f,
    const float* __restrict__ bhh_f,
    const float* __restrict__ whh_b,
    const float* __restrict__ bhh_b,
    const _Float16* __restrict__ xp_rz,
    const _Float16* __restrict__ xp_n,
    unsigned short* __restrict__ allh)
{
    __shared__ __align__(16) _Float16 hbuf[2][192];
    const int bd = blockIdx.x;
    const int b = bd >> 1, dir = bd & 1;
    const int tid = threadIdx.x;
    const int j = tid >> 2, c = tid & 3;
    const float* whh = dir ? whh_b : whh_f;
    const float* bhh = dir ? bhh_b : bhh_f;

    // W_hh in VGPRs as f16 (2^-11 rel err from f32)
    h2 wr[24], wz[24], wn[24];
    {
        const float* r0 = whh + (long)(0*192 + j)*192 + c*48;
        const float* r1 = whh + (long)(1*192 + j)*192 + c*48;
        const float* r2 = whh + (long)(2*192 + j)*192 + c*48;
        #pragma unroll
        for (int kk = 0; kk < 24; ++kk){
            wr[kk] = h2{(_Float16)r0[2*kk], (_Float16)r0[2*kk+1]};
            wz[kk] = h2{(_Float16)r1[2*kk], (_Float16)r1[2*kk+1]};
            wn[kk] = h2{(_Float16)r2[2*kk], (_Float16)r2[2*kk+1]};
        }
    }
    const float bhr = bhh[j];
    const float bhz = bhh[192 + j];
    const float bhn = bhh[384 + j];

    if (tid < 192) hbuf[0][tid] = (_Float16)0.f;
    __syncthreads();

    const _Float16* xrz = xp_rz + (size_t)b*L_*768 + dir*384 + j*2;
    const _Float16* xnp = xp_n  + (size_t)b*L_*384 + dir*192 + j;
    unsigned short* hout = allh + (size_t)b*L_*384 + dir*192 + j;

    float hprev = 0.f;
    // 3-deep prefetch pipeline: px0/pn0 = step t, px1 = t+1, px2 = t+2
    h2 px0 = h2{(_Float16)0.f,(_Float16)0.f}, px1 = px0, px2 = px0;
    _Float16 pn0 = (_Float16)0.f, pn1 = pn0, pn2 = pn0;
    if (c == 0){
        int q0 = dir ? (L_-1) : 0, q1 = dir ? (L_-2) : 1, q2 = dir ? (L_-3) : 2;
        px0 = *(const h2*)(xrz + (size_t)q0*768); pn0 = xnp[(size_t)q0*384];
        px1 = *(const h2*)(xrz + (size_t)q1*768); pn1 = xnp[(size_t)q1*384];
        px2 = *(const h2*)(xrz + (size_t)q2*768); pn2 = xnp[(size_t)q2*384];
    }

    for (int t = 0; t < L_; ++t){
        h2 pxl = px2; _Float16 pnl = pn2;
        if (c == 0){
            int tn = (t + 3 < L_) ? (t + 3) : (L_-1);
            int posn = dir ? (L_-1 - tn) : tn;
            pxl = *(const h2*)(xrz + (size_t)posn*768);
            pnl = xnp[(size_t)posn*384];
        }

        const int cur = t & 1, nxt = cur ^ 1;
        float ar = 0.f, az = 0.f, an = 0.f;
        const h8* hp = (const h8*)(&hbuf[cur][c*48]);
        #pragma unroll
        for (int i = 0; i < 6; ++i){
            h8 hv = hp[i];
            #pragma unroll
            for (int q = 0; q < 4; ++q){
                h2 hx = h2{hv[2*q], hv[2*q+1]};
                ar = __builtin_amdgcn_fdot2(wr[i*4+q], hx, ar, false);
                az = __builtin_amdgcn_fdot2(wz[i*4+q], hx, az, false);
                an = __builtin_amdgcn_fdot2(wn[i*4+q], hx, an, false);
            }
        }
        ar = quad_allreduce(ar);
        az = quad_allreduce(az);
        an = quad_allreduce(an);

        if (c == 0){
            float xr = (float)px0[0], xz = (float)px0[1], xn = (float)pn0;
            float r = __builtin_amdgcn_rcpf(1.f + __expf(-(xr + ar + bhr)));
            float z = __builtin_amdgcn_rcpf(1.f + __expf(-(xz + az + bhz)));
            float narg = fmaf(r, an + bhn, xn);
            float nv = fmaf(2.f, __builtin_amdgcn_rcpf(1.f + __expf(-2.f*narg)), -1.f);
            float h = fmaf(z, hprev - nv, nv);
            hprev = h;
            hbuf[nxt][j] = (_Float16)h;
            int pos = dir ? (L_-1 - t) : t;
            hout[(size_t)pos*384] = f2bf(h);
        }
        px0 = px1; pn0 = pn1;
        px1 = px2; pn1 = pn2;
        px2 = pxl; pn2 = pnl;
        // barrier WITHOUT vmcnt(0): only LDS visibility is required here.
        // Global h-stores and the t+3 xp prefetch stay in flight across it;
        // the compiler's own vmcnt(N) waits before consumption handle loads.
        __asm__ __volatile__("s_waitcnt lgkmcnt(0)\n\ts_barrier" ::: "memory");
    }
}

// ---------------- Kernel 3: start/end gather, f32 output ----------------
__global__ __launch_bounds__(256) void k_gather(
    const int* __restrict__ start_ids,
    const int* __restrict__ end_ids,
    const unsigned short* __restrict__ allh,
    float* __restrict__ out)
{
    int t = blockIdx.x * 256 + threadIdx.x;       // 1,572,864 threads, 8 elems each
    int k8 = t % 96;
    int rest = t / 96;
    int s = rest & 511;
    int b = rest >> 9;
    int k = k8 * 8;
    int off, pos;
    if (k < 384){ off = k;       pos = start_ids[b*512 + s]; }
    else        { off = k - 384; pos = end_ids  [b*512 + s]; }
    pos = (pos < 0) ? 0 : ((pos > 2047) ? 2047 : pos);
    const unsigned short* src = allh + (size_t)(b*2048 + pos)*384 + off;
    uint4 v = *(const uint4*)src;
    const unsigned short* h = (const unsigned short*)&v;
    float* outf = out + (size_t)t*8;
    f4 lo = {bf2f(h[0]), bf2f(h[1]), bf2f(h[2]), bf2f(h[3])};
    f4 hi = {bf2f(h[4]), bf2f(h[5]), bf2f(h[6]), bf2f(h[7])};
    *(f4*)outf = lo;
    *(f4*)(outf + 4) = hi;
}

extern "C" void kernel_launch(void* const* d_in, const int* in_sizes, int n_in,
                              void* d_out, int out_size, void* d_ws, size_t ws_size,
                              hipStream_t stream)
{
    const int* ids   = (const int*)d_in[0];
    const int* sids  = (const int*)d_in[1];
    const int* eids  = (const int*)d_in[2];
    const float* emb  = (const float*)d_in[3];
    const float* wihf = (const float*)d_in[4];
    const float* whhf = (const float*)d_in[5];
    const float* bihf = (const float*)d_in[6];
    const float* bhhf = (const float*)d_in[7];
    const float* wihb = (const float*)d_in[8];
    const float* whhb = (const float*)d_in[9];
    const float* bihb = (const float*)d_in[10];
    const float* bhhb = (const float*)d_in[11];

    _Float16* xp_rz = (_Float16*)d_ws;
    _Float16* xp_n  = (_Float16*)((char*)d_ws + XP_RZ_BYTES);
    unsigned short* allh = (unsigned short*)((char*)d_ws + XP_RZ_BYTES + XP_N_BYTES);

    dim3 g1(512, 9);   // 512 M-tiles x 9 N-tiles (1152/128)
    k_proj<<<g1, 256, 0, stream>>>(ids, emb, wihf, wihb, bihf, bihb, xp_rz, xp_n);
    k_scan<<<64, 768, 0, stream>>>(whhf, bhhf, whhb, bhhb, xp_rz, xp_n, allh);
    k_gather<<<6144, 256, 0, stream>>>(sids, eids, allh, (float*)d_out);
}